// Round 6
// baseline (163.142 us; speedup 1.0000x reference)
//
#include <hip/hip_runtime.h>

// PhysicsInformedLoss on (16,3,1024,512) f32 y_hat + (16,2,1024,512) i32 x_in.
// R6: R4 structure (wave=row, aligned dwordx4, shfl j-neighbors, reg rotation)
// with RROWS=4 -> 1024 blocks = 16 waves/CU (grid- and VGPR-limits aligned),
// launch_bounds(256,2) (NO forced VGPR cap -> no spills), fused ticket finalize.

namespace {
constexpr int NXc   = 1024;
constexpr int NYc   = 512;
constexpr int NXYc  = NXc * NYc;
constexpr int NBc   = 16;
constexpr int NTHR  = 256;
constexpr int NACC  = 10;
constexpr int RROWS = 4;
constexpr int NCHUNK = NXc / RROWS;            // 256 row-chunks
constexpr int NWAVE  = NBc * NCHUNK;           // 4096 waves
constexpr int NBLK   = NWAVE / (NTHR / 64);    // 1024 blocks
// acc: 0 s_div2, 1 s_resx2, 2 s_resy2, 3 n_interior,
//      4 s_noslip, 5 n_noslip, 6 s_inlet, 7 n_inlet, 8 s_outlet, 9 n_outlet
}

struct Frow { float4 xl, xh, yl, yh, pl, ph; };

__device__ __forceinline__ Frow ldrow(const float* __restrict__ ux,
                                      const float* __restrict__ uy,
                                      const float* __restrict__ pp, int off) {
  Frow f;
  f.xl = *reinterpret_cast<const float4*>(ux + off);
  f.xh = *reinterpret_cast<const float4*>(ux + off + 4);
  f.yl = *reinterpret_cast<const float4*>(uy + off);
  f.yh = *reinterpret_cast<const float4*>(uy + off + 4);
  f.pl = *reinterpret_cast<const float4*>(pp + off);
  f.ph = *reinterpret_cast<const float4*>(pp + off + 4);
  return f;
}

__global__ __launch_bounds__(NTHR, 2) void pil_main(const float* __restrict__ y,
                                                    const int* __restrict__ xin,
                                                    double* __restrict__ partial,
                                                    unsigned int* __restrict__ ticket,
                                                    float* __restrict__ out) {
  constexpr double DXd = 0.26 / 1023.0;
  constexpr double DYd = 0.12 / 511.0;
  const float INV2DX = (float)(1.0 / (2.0 * DXd));
  const float INV2DY = (float)(1.0 / (2.0 * DYd));
  const float INVDX2 = (float)(1.0 / (DXd * DXd));
  const float INVDY2 = (float)(1.0 / (DYd * DYd));
  constexpr float NU = 1e-4f;
  constexpr float U_INLET = 0.1f;

  const int l     = threadIdx.x & 63;
  const int wv    = (blockIdx.x << 2) | (threadIdx.x >> 6);
  const int chunk = wv & (NCHUNK - 1);
  const int b     = wv >> 8;
  const int i0    = chunk * RROWS;
  const int jc    = l << 3;                  // col base, 8 cols/lane

  const float* __restrict__ ux = y + (size_t)b * 3 * NXYc;
  const float* __restrict__ uy = ux + NXYc;
  const float* __restrict__ pp = ux + 2 * NXYc;
  const int*   __restrict__ rp = xin + (size_t)(2 * b + 1) * NXYc;

  float a[NACC];
#pragma unroll
  for (int k = 0; k < NACC; ++k) a[k] = 0.f;

  // rotation: prev/cur/next field rows; region codes for cur row
  Frow P = ldrow(ux, uy, pp, (i0 > 0 ? i0 - 1 : 0) * NYc + jc);
  Frow C = ldrow(ux, uy, pp, i0 * NYc + jc);
  Frow N = ldrow(ux, uy, pp, (i0 + 1) * NYc + jc);
  int4 rCl = *reinterpret_cast<const int4*>(rp + i0 * NYc + jc);
  int4 rCh = *reinterpret_cast<const int4*>(rp + i0 * NYc + jc + 4);

#pragma unroll
  for (int s = 0; s < RROWS; ++s) {
    const int i = i0 + s;

    Frow F = C;
    int4 rFl = rCl, rFh = rCh;
    if (s < RROWS - 1) {
      F = ldrow(ux, uy, pp, min(i + 2, NXc - 1) * NYc + jc);
      rFl = *reinterpret_cast<const int4*>(rp + (i + 1) * NYc + jc);
      rFh = *reinterpret_cast<const int4*>(rp + (i + 1) * NYc + jc + 4);
    }

    const float cx[8]  = {C.xl.x, C.xl.y, C.xl.z, C.xl.w, C.xh.x, C.xh.y, C.xh.z, C.xh.w};
    const float cy_[8] = {C.yl.x, C.yl.y, C.yl.z, C.yl.w, C.yh.x, C.yh.y, C.yh.z, C.yh.w};
    const float cp_[8] = {C.pl.x, C.pl.y, C.pl.z, C.pl.w, C.ph.x, C.ph.y, C.ph.z, C.ph.w};
    const float pxA[8] = {P.xl.x, P.xl.y, P.xl.z, P.xl.w, P.xh.x, P.xh.y, P.xh.z, P.xh.w};
    const float pyA[8] = {P.yl.x, P.yl.y, P.yl.z, P.yl.w, P.yh.x, P.yh.y, P.yh.z, P.yh.w};
    const float ppA[8] = {P.pl.x, P.pl.y, P.pl.z, P.pl.w, P.ph.x, P.ph.y, P.ph.z, P.ph.w};
    const float nxA[8] = {N.xl.x, N.xl.y, N.xl.z, N.xl.w, N.xh.x, N.xh.y, N.xh.z, N.xh.w};
    const float nyA[8] = {N.yl.x, N.yl.y, N.yl.z, N.yl.w, N.yh.x, N.yh.y, N.yh.z, N.yh.w};
    const float npA[8] = {N.pl.x, N.pl.y, N.pl.z, N.pl.w, N.ph.x, N.ph.y, N.ph.z, N.ph.w};
    const int   rA[8]  = {rCl.x, rCl.y, rCl.z, rCl.w, rCh.x, rCh.y, rCh.z, rCh.w};

    // cur-row j-neighbors across lanes (2 shuffles per field)
    float lxx = __shfl_up(cx[7], 1, 64);    if (l == 0)  lxx = cx[0];
    float rxx = __shfl_down(cx[0], 1, 64);  if (l == 63) rxx = cx[7];
    float lyy = __shfl_up(cy_[7], 1, 64);   if (l == 0)  lyy = cy_[0];
    float ryy = __shfl_down(cy_[0], 1, 64); if (l == 63) ryy = cy_[7];
    float lpp = __shfl_up(cp_[7], 1, 64);   if (l == 0)  lpp = cp_[0];
    float rpp = __shfl_down(cp_[0], 1, 64); if (l == 63) rpp = cp_[7];

    const bool irow = (i >= 1) & (i <= NXc - 2);

#pragma unroll
    for (int e = 0; e < 8; ++e) {
      const int   r    = rA[e];
      const float c_ux = cx[e], c_uy = cy_[e];
      const float uxm = (e == 0) ? lxx : cx[e - 1];
      const float uxp = (e == 7) ? rxx : cx[e + 1];
      const float uym = (e == 0) ? lyy : cy_[e - 1];
      const float uyp = (e == 7) ? ryy : cy_[e + 1];
      const float pm_ = (e == 0) ? lpp : cp_[e - 1];
      const float pq_ = (e == 7) ? rpp : cp_[e + 1];

      const float ddx_ux = (nxA[e] - pxA[e]) * INV2DX;
      const float ddy_ux = (uxp - uxm) * INV2DY;
      const float ddx_uy = (nyA[e] - pyA[e]) * INV2DX;
      const float ddy_uy = (uyp - uym) * INV2DY;

      const bool jedge = ((l == 0) & (e == 0)) | ((l == 63) & (e == 7));
      const bool interior = (r >= 1) & irow & (!jedge);
      if (interior) {
        const float dv    = ddx_ux + ddy_uy;
        const float d2xux = (nxA[e] - 2.f * c_ux + pxA[e]) * INVDX2;
        const float d2yux = (uxp - 2.f * c_ux + uxm) * INVDY2;
        const float d2xuy = (nyA[e] - 2.f * c_uy + pyA[e]) * INVDX2;
        const float d2yuy = (uyp - 2.f * c_uy + uym) * INVDY2;
        const float ddx_p = (npA[e] - ppA[e]) * INV2DX;
        const float ddy_p = (pq_ - pm_) * INV2DY;
        const float rx = c_ux * ddx_ux + c_uy * ddy_ux + ddx_p - NU * (d2xux + d2yux);
        const float ry = c_ux * ddx_uy + c_uy * ddy_uy + ddy_p - NU * (d2xuy + d2yuy);
        a[0] += dv * dv;
        a[1] += rx * rx;
        a[2] += ry * ry;
        a[3] += 1.f;
      }
      if ((r == 0) | (r == 2)) {
        a[4] += c_ux * c_ux + c_uy * c_uy;
        a[5] += 1.f;
      }
      if (r == 3) {
        const float d = c_ux - U_INLET;
        a[6] += d * d + c_uy * c_uy;
        a[7] += 1.f;
      }
      if (r == 4) {
        a[8] += ddx_ux * ddx_ux;
        a[9] += 1.f;
      }
    }

    if (s < RROWS - 1) {   // rotate pipeline
      P = C; C = N; N = F;
      rCl = rFl; rCh = rFh;
    }
  }

  // wave-64 shuffle reduction per accumulator
#pragma unroll
  for (int k = 0; k < NACC; ++k) {
    float v = a[k];
#pragma unroll
    for (int off = 32; off > 0; off >>= 1) v += __shfl_down(v, off, 64);
    a[k] = v;
  }

  __shared__ double sacc[NTHR / 64][NACC];
  const int lane = threadIdx.x & 63;
  const int wave = threadIdx.x >> 6;
  if (lane == 0) {
#pragma unroll
    for (int k = 0; k < NACC; ++k) sacc[wave][k] = (double)a[k];
  }
  __syncthreads();
  if (threadIdx.x < NACC) {
    double s = 0.0;
#pragma unroll
    for (int w = 0; w < NTHR / 64; ++w) s += sacc[w][threadIdx.x];
    partial[threadIdx.x * NBLK + blockIdx.x] = s;   // SoA [NACC][NBLK]
  }

  // ----- fused finalize: last block to arrive reduces all partials -----
  __threadfence();
  __shared__ bool amLast;
  if (threadIdx.x == 0)
    amLast = (atomicAdd(ticket, 1u) == (unsigned)(NBLK - 1));
  __syncthreads();
  if (!amLast) return;
  __threadfence();

  __shared__ double sw[NACC][NTHR / 64];
  const int t = threadIdx.x;
#pragma unroll
  for (int k = 0; k < NACC; ++k) {
    double v = 0.0;
    for (int bb = t; bb < NBLK; bb += NTHR) v += partial[k * NBLK + bb];
#pragma unroll
    for (int off = 32; off > 0; off >>= 1) v += __shfl_down(v, off, 64);
    if (lane == 0) sw[k][wave] = v;
  }
  __syncthreads();
  if (t == 0) {
    double acc[NACC];
#pragma unroll
    for (int k = 0; k < NACC; ++k) {
      double s = 0.0;
#pragma unroll
      for (int w = 0; w < NTHR / 64; ++w) s += sw[k][w];
      acc[k] = s;
    }
    const double l_cont = acc[0] / fmax(acc[3], 1.0);
    const double l_mom  = (acc[1] + acc[2]) / fmax(acc[3], 1.0);
    const double l_bc   = acc[4] / fmax(acc[5], 1.0)
                        + acc[6] / fmax(acc[7], 1.0)
                        + acc[8] / fmax(acc[9], 1.0);
    const double total  = 1.0 * l_cont + 0.1 * l_mom + 1.0 * l_bc;
    out[0] = (float)l_cont;
    out[1] = (float)l_mom;
    out[2] = (float)l_bc;
    out[3] = (float)total;
  }
}

extern "C" void kernel_launch(void* const* d_in, const int* in_sizes, int n_in,
                              void* d_out, int out_size, void* d_ws, size_t ws_size,
                              hipStream_t stream) {
  const float* y   = (const float*)d_in[0];   // y_hat (16,3,1024,512) f32
  const int*   xin = (const int*)d_in[1];     // x_in  (16,2,1024,512) i32
  double* partial  = (double*)d_ws;           // NACC*NBLK*8 = 80 KB
  unsigned int* ticket = (unsigned int*)((char*)d_ws + (size_t)NACC * NBLK * 8);

  hipMemsetAsync(ticket, 0, sizeof(unsigned int), stream);
  pil_main<<<NBLK, NTHR, 0, stream>>>(y, xin, partial, ticket, (float*)d_out);
}

// Round 7
// 49.510 us; speedup vs baseline: 3.2951x; 3.2951x over previous
//
#include <hip/hip_runtime.h>

// PhysicsInformedLoss on (16,3,1024,512) f32 y_hat + (16,2,1024,512) i32 x_in.
// R7: R6 main structure (wave=row, aligned dwordx4, shfl j-neighbors, RROWS=4
// -> 1024 blocks = 16 waves/CU) but WITHOUT the fused ticket finalize:
// R5/R6 showed per-block __threadfence() (agent-scope -> L2 wb/inv on
// non-coherent XCD L2s) serializes ~150us. Two-kernel form instead.

namespace {
constexpr int NXc   = 1024;
constexpr int NYc   = 512;
constexpr int NXYc  = NXc * NYc;
constexpr int NBc   = 16;
constexpr int NTHR  = 256;
constexpr int NACC  = 10;
constexpr int RROWS = 4;
constexpr int NCHUNK = NXc / RROWS;            // 256 row-chunks
constexpr int NWAVE  = NBc * NCHUNK;           // 4096 waves
constexpr int NBLK   = NWAVE / (NTHR / 64);    // 1024 blocks
// acc: 0 s_div2, 1 s_resx2, 2 s_resy2, 3 n_interior,
//      4 s_noslip, 5 n_noslip, 6 s_inlet, 7 n_inlet, 8 s_outlet, 9 n_outlet
}

struct Frow { float4 xl, xh, yl, yh, pl, ph; };

__device__ __forceinline__ Frow ldrow(const float* __restrict__ ux,
                                      const float* __restrict__ uy,
                                      const float* __restrict__ pp, int off) {
  Frow f;
  f.xl = *reinterpret_cast<const float4*>(ux + off);
  f.xh = *reinterpret_cast<const float4*>(ux + off + 4);
  f.yl = *reinterpret_cast<const float4*>(uy + off);
  f.yh = *reinterpret_cast<const float4*>(uy + off + 4);
  f.pl = *reinterpret_cast<const float4*>(pp + off);
  f.ph = *reinterpret_cast<const float4*>(pp + off + 4);
  return f;
}

__global__ __launch_bounds__(NTHR, 2) void pil_main(const float* __restrict__ y,
                                                    const int* __restrict__ xin,
                                                    double* __restrict__ partial) {
  constexpr double DXd = 0.26 / 1023.0;
  constexpr double DYd = 0.12 / 511.0;
  const float INV2DX = (float)(1.0 / (2.0 * DXd));
  const float INV2DY = (float)(1.0 / (2.0 * DYd));
  const float INVDX2 = (float)(1.0 / (DXd * DXd));
  const float INVDY2 = (float)(1.0 / (DYd * DYd));
  constexpr float NU = 1e-4f;
  constexpr float U_INLET = 0.1f;

  const int l     = threadIdx.x & 63;
  const int wv    = (blockIdx.x << 2) | (threadIdx.x >> 6);
  const int chunk = wv & (NCHUNK - 1);
  const int b     = wv >> 8;
  const int i0    = chunk * RROWS;
  const int jc    = l << 3;                  // col base, 8 cols/lane

  const float* __restrict__ ux = y + (size_t)b * 3 * NXYc;
  const float* __restrict__ uy = ux + NXYc;
  const float* __restrict__ pp = ux + 2 * NXYc;
  const int*   __restrict__ rp = xin + (size_t)(2 * b + 1) * NXYc;

  float a[NACC];
#pragma unroll
  for (int k = 0; k < NACC; ++k) a[k] = 0.f;

  // rotation: prev/cur/next field rows; region codes for cur row
  Frow P = ldrow(ux, uy, pp, (i0 > 0 ? i0 - 1 : 0) * NYc + jc);
  Frow C = ldrow(ux, uy, pp, i0 * NYc + jc);
  Frow N = ldrow(ux, uy, pp, (i0 + 1) * NYc + jc);
  int4 rCl = *reinterpret_cast<const int4*>(rp + i0 * NYc + jc);
  int4 rCh = *reinterpret_cast<const int4*>(rp + i0 * NYc + jc + 4);

#pragma unroll
  for (int s = 0; s < RROWS; ++s) {
    const int i = i0 + s;

    Frow F = C;
    int4 rFl = rCl, rFh = rCh;
    if (s < RROWS - 1) {
      F = ldrow(ux, uy, pp, min(i + 2, NXc - 1) * NYc + jc);
      rFl = *reinterpret_cast<const int4*>(rp + (i + 1) * NYc + jc);
      rFh = *reinterpret_cast<const int4*>(rp + (i + 1) * NYc + jc + 4);
    }

    const float cx[8]  = {C.xl.x, C.xl.y, C.xl.z, C.xl.w, C.xh.x, C.xh.y, C.xh.z, C.xh.w};
    const float cy_[8] = {C.yl.x, C.yl.y, C.yl.z, C.yl.w, C.yh.x, C.yh.y, C.yh.z, C.yh.w};
    const float cp_[8] = {C.pl.x, C.pl.y, C.pl.z, C.pl.w, C.ph.x, C.ph.y, C.ph.z, C.ph.w};
    const float pxA[8] = {P.xl.x, P.xl.y, P.xl.z, P.xl.w, P.xh.x, P.xh.y, P.xh.z, P.xh.w};
    const float pyA[8] = {P.yl.x, P.yl.y, P.yl.z, P.yl.w, P.yh.x, P.yh.y, P.yh.z, P.yh.w};
    const float ppA[8] = {P.pl.x, P.pl.y, P.pl.z, P.pl.w, P.ph.x, P.ph.y, P.ph.z, P.ph.w};
    const float nxA[8] = {N.xl.x, N.xl.y, N.xl.z, N.xl.w, N.xh.x, N.xh.y, N.xh.z, N.xh.w};
    const float nyA[8] = {N.yl.x, N.yl.y, N.yl.z, N.yl.w, N.yh.x, N.yh.y, N.yh.z, N.yh.w};
    const float npA[8] = {N.pl.x, N.pl.y, N.pl.z, N.pl.w, N.ph.x, N.ph.y, N.ph.z, N.ph.w};
    const int   rA[8]  = {rCl.x, rCl.y, rCl.z, rCl.w, rCh.x, rCh.y, rCh.z, rCh.w};

    // cur-row j-neighbors across lanes (2 shuffles per field)
    float lxx = __shfl_up(cx[7], 1, 64);    if (l == 0)  lxx = cx[0];
    float rxx = __shfl_down(cx[0], 1, 64);  if (l == 63) rxx = cx[7];
    float lyy = __shfl_up(cy_[7], 1, 64);   if (l == 0)  lyy = cy_[0];
    float ryy = __shfl_down(cy_[0], 1, 64); if (l == 63) ryy = cy_[7];
    float lpp = __shfl_up(cp_[7], 1, 64);   if (l == 0)  lpp = cp_[0];
    float rpp = __shfl_down(cp_[0], 1, 64); if (l == 63) rpp = cp_[7];

    const bool irow = (i >= 1) & (i <= NXc - 2);

#pragma unroll
    for (int e = 0; e < 8; ++e) {
      const int   r    = rA[e];
      const float c_ux = cx[e], c_uy = cy_[e];
      const float uxm = (e == 0) ? lxx : cx[e - 1];
      const float uxp = (e == 7) ? rxx : cx[e + 1];
      const float uym = (e == 0) ? lyy : cy_[e - 1];
      const float uyp = (e == 7) ? ryy : cy_[e + 1];
      const float pm_ = (e == 0) ? lpp : cp_[e - 1];
      const float pq_ = (e == 7) ? rpp : cp_[e + 1];

      const float ddx_ux = (nxA[e] - pxA[e]) * INV2DX;
      const float ddy_ux = (uxp - uxm) * INV2DY;
      const float ddx_uy = (nyA[e] - pyA[e]) * INV2DX;
      const float ddy_uy = (uyp - uym) * INV2DY;

      const bool jedge = ((l == 0) & (e == 0)) | ((l == 63) & (e == 7));
      const bool interior = (r >= 1) & irow & (!jedge);
      if (interior) {
        const float dv    = ddx_ux + ddy_uy;
        const float d2xux = (nxA[e] - 2.f * c_ux + pxA[e]) * INVDX2;
        const float d2yux = (uxp - 2.f * c_ux + uxm) * INVDY2;
        const float d2xuy = (nyA[e] - 2.f * c_uy + pyA[e]) * INVDX2;
        const float d2yuy = (uyp - 2.f * c_uy + uym) * INVDY2;
        const float ddx_p = (npA[e] - ppA[e]) * INV2DX;
        const float ddy_p = (pq_ - pm_) * INV2DY;
        const float rx = c_ux * ddx_ux + c_uy * ddy_ux + ddx_p - NU * (d2xux + d2yux);
        const float ry = c_ux * ddx_uy + c_uy * ddy_uy + ddy_p - NU * (d2xuy + d2yuy);
        a[0] += dv * dv;
        a[1] += rx * rx;
        a[2] += ry * ry;
        a[3] += 1.f;
      }
      if ((r == 0) | (r == 2)) {
        a[4] += c_ux * c_ux + c_uy * c_uy;
        a[5] += 1.f;
      }
      if (r == 3) {
        const float d = c_ux - U_INLET;
        a[6] += d * d + c_uy * c_uy;
        a[7] += 1.f;
      }
      if (r == 4) {
        a[8] += ddx_ux * ddx_ux;
        a[9] += 1.f;
      }
    }

    if (s < RROWS - 1) {   // rotate pipeline
      P = C; C = N; N = F;
      rCl = rFl; rCh = rFh;
    }
  }

  // wave-64 shuffle reduction per accumulator
#pragma unroll
  for (int k = 0; k < NACC; ++k) {
    float v = a[k];
#pragma unroll
    for (int off = 32; off > 0; off >>= 1) v += __shfl_down(v, off, 64);
    a[k] = v;
  }

  __shared__ double sacc[NTHR / 64][NACC];
  const int lane = threadIdx.x & 63;
  const int wave = threadIdx.x >> 6;
  if (lane == 0) {
#pragma unroll
    for (int k = 0; k < NACC; ++k) sacc[wave][k] = (double)a[k];
  }
  __syncthreads();
  if (threadIdx.x < NACC) {
    double s = 0.0;
#pragma unroll
    for (int w = 0; w < NTHR / 64; ++w) s += sacc[w][threadIdx.x];
    partial[threadIdx.x * NBLK + blockIdx.x] = s;   // SoA [NACC][NBLK]
  }
}

__global__ __launch_bounds__(NTHR) void pil_finalize(const double* __restrict__ partial,
                                                     float* __restrict__ out) {
  __shared__ double sw[NACC][NTHR / 64];
  const int t = threadIdx.x;
  const int lane = t & 63, wave = t >> 6;
#pragma unroll
  for (int k = 0; k < NACC; ++k) {
    double v = 0.0;
    for (int b = t; b < NBLK; b += NTHR) v += partial[k * NBLK + b];
#pragma unroll
    for (int off = 32; off > 0; off >>= 1) v += __shfl_down(v, off, 64);
    if (lane == 0) sw[k][wave] = v;
  }
  __syncthreads();
  if (t == 0) {
    double acc[NACC];
#pragma unroll
    for (int k = 0; k < NACC; ++k) {
      double s = 0.0;
#pragma unroll
      for (int w = 0; w < NTHR / 64; ++w) s += sw[k][w];
      acc[k] = s;
    }
    const double l_cont = acc[0] / fmax(acc[3], 1.0);
    const double l_mom  = (acc[1] + acc[2]) / fmax(acc[3], 1.0);
    const double l_bc   = acc[4] / fmax(acc[5], 1.0)
                        + acc[6] / fmax(acc[7], 1.0)
                        + acc[8] / fmax(acc[9], 1.0);
    const double total  = 1.0 * l_cont + 0.1 * l_mom + 1.0 * l_bc;
    out[0] = (float)l_cont;
    out[1] = (float)l_mom;
    out[2] = (float)l_bc;
    out[3] = (float)total;
  }
}

extern "C" void kernel_launch(void* const* d_in, const int* in_sizes, int n_in,
                              void* d_out, int out_size, void* d_ws, size_t ws_size,
                              hipStream_t stream) {
  const float* y   = (const float*)d_in[0];   // y_hat (16,3,1024,512) f32
  const int*   xin = (const int*)d_in[1];     // x_in  (16,2,1024,512) i32
  double* partial  = (double*)d_ws;           // NACC*NBLK*8 = 80 KB

  pil_main<<<NBLK, NTHR, 0, stream>>>(y, xin, partial);
  pil_finalize<<<1, NTHR, 0, stream>>>(partial, (float*)d_out);
}